// Round 13
// baseline (239.894 us; speedup 1.0000x reference)
//
#include <hip/hip_runtime.h>
#include <hip/hip_bf16.h>
#include <hip/hip_fp16.h>

#define FD 128
#define CBW 128           // coarse bucket width: bucket = dst >> 7
#define NBK 512           // max buckets (50000/128 = 391)

typedef _Float16 half8 __attribute__((ext_vector_type(8)));
typedef float f32x4 __attribute__((ext_vector_type(4)));

// ---------------- tiny prep: W1,W2 -> W^T fp16 (blocks 0,1); zero ccnt (block 2) ----------------
__global__ __launch_bounds__(256) void k_wz(const float* __restrict__ W1,
                                            const float* __restrict__ W2,
                                            __half* __restrict__ T1,
                                            __half* __restrict__ T2,
                                            int* __restrict__ ccnt, int nb) {
    const int t = threadIdx.x;
    if (blockIdx.x == 2) {
        for (int i = t; i < nb; i += 256) ccnt[i] = 0;
        return;
    }
    __shared__ float sw[128 * 129];
    const float* W = blockIdx.x ? W2 : W1;
    __half* T = blockIdx.x ? T2 : T1;
#pragma unroll
    for (int i = 0; i < 64; i++) {
        int idx = i * 256 + t;
        sw[(idx >> 7) * 129 + (idx & 127)] = W[idx];
    }
    __syncthreads();
#pragma unroll
    for (int i = 0; i < 32; i++) {
        int o = i * 256 + t;
        int c = o >> 6, kp = o & 63;
        float lo = sw[(kp * 2) * 129 + c];
        float hi = sw[(kp * 2 + 1) * 129 + c];
        *(__half2*)&T[c * 128 + kp * 2] = __floats2half2_rn(lo, hi);
    }
}

// H stored as two feature slabs: H[slab][n][64], slab = feature>>6.
__device__ __forceinline__ void gemm_core(const half8 A[4],
                                          const __half* __restrict__ Wt,
                                          const float* __restrict__ a_s,
                                          const float* __restrict__ a_d,
                                          __half* __restrict__ H,
                                          float* __restrict__ as_,
                                          float* __restrict__ ad_,
                                          int n, int row0, int g, int c16) {
    f32x4 acc[8];
#pragma unroll
    for (int ct = 0; ct < 8; ct++) acc[ct] = (f32x4){0.f, 0.f, 0.f, 0.f};
#pragma unroll
    for (int ct = 0; ct < 8; ct++) {
        const __half* wp = &Wt[(ct * 16 + c16) * 128 + g * 8];
#pragma unroll
        for (int kc = 0; kc < 4; kc++) {
            half8 b = *(const half8*)(wp + kc * 32);
            acc[ct] = __builtin_amdgcn_mfma_f32_16x16x32_f16(A[kc], b, acc[ct], 0, 0, 0);
        }
    }
    float asv[8], adv[8];
#pragma unroll
    for (int ct = 0; ct < 8; ct++) {
        asv[ct] = a_s[ct * 16 + c16];
        adv[ct] = a_d[ct * 16 + c16];
    }
#pragma unroll
    for (int r = 0; r < 4; r++) {
        const int row = row0 + g * 4 + r;
        float vs = 0.f, vd = 0.f;
#pragma unroll
        for (int ct = 0; ct < 8; ct++) {
            float v = acc[ct][r];
            vs += v * asv[ct];
            vd += v * adv[ct];
            if (row < n) {
                size_t hoff = (size_t)(ct >> 2) * ((size_t)n * 64)
                            + (size_t)row * 64 + (ct & 3) * 16 + c16;
                H[hoff] = __float2half(v);
            }
        }
#pragma unroll
        for (int off = 8; off; off >>= 1) {
            vs += __shfl_xor(vs, off, 16);
            vd += __shfl_xor(vd, off, 16);
        }
        if (c16 == 0 && row < n) { as_[row] = vs; ad_[row] = vd; }
    }
}

// ---------------- fat: coarse histogram (blocks 0..255) || layer-1 GEMM (blocks 256+) ----------------
__global__ __launch_bounds__(256) void k_pg(const int* __restrict__ dst,
                                            int* __restrict__ ccnt, int e, int nb,
                                            const float* __restrict__ X,
                                            const __half* __restrict__ Wt,
                                            const float* __restrict__ a_s,
                                            const float* __restrict__ a_d,
                                            __half* __restrict__ H,
                                            float* __restrict__ as_,
                                            float* __restrict__ ad_, int n) {
    __shared__ int lh[NBK];
    const int t = threadIdx.x;
    if (blockIdx.x < 256) {
        for (int i = t; i < NBK; i += 256) lh[i] = 0;
        __syncthreads();
        for (int i = blockIdx.x * 256 + t; i < e; i += 256 * 256)
            atomicAdd(&lh[dst[i] >> 7], 1);
        __syncthreads();
        for (int i = t; i < nb; i += 256) {
            int c = lh[i];
            if (c) atomicAdd(&ccnt[i], c);
        }
    } else {
        const int bid = blockIdx.x - 256;
        const int wave = t >> 6, lane = t & 63;
        const int g = lane >> 4, c16 = lane & 15;
        const int row0 = bid * 64 + wave * 16;
        half8 A[4];
        {
            int row = row0 + c16;
            int rc = (row < n) ? row : (n - 1);
            const float* xp = &X[(size_t)rc * 128 + g * 8];
#pragma unroll
            for (int kc = 0; kc < 4; kc++) {
                float4 x0 = *(const float4*)(xp + kc * 32);
                float4 x1 = *(const float4*)(xp + kc * 32 + 4);
                half8 a;
                a[0] = (_Float16)x0.x; a[1] = (_Float16)x0.y;
                a[2] = (_Float16)x0.z; a[3] = (_Float16)x0.w;
                a[4] = (_Float16)x1.x; a[5] = (_Float16)x1.y;
                a[6] = (_Float16)x1.z; a[7] = (_Float16)x1.w;
                A[kc] = a;
            }
        }
        gemm_core(A, Wt, a_s, a_d, H, as_, ad_, n, row0, g, c16);
    }
}

// ---------------- scan of coarse counts (single block, nb<=1024) ----------------
__global__ void k_cscan(const int* __restrict__ ccnt, int* __restrict__ cbase,
                        int* __restrict__ ccur, int nb, int* __restrict__ rowptr, int n) {
    __shared__ int wsum[16];
    __shared__ int woff[17];
    const int t = threadIdx.x, lane = t & 63, wid = t >> 6;
    int v = (t < nb) ? ccnt[t] : 0;
    int s = v;
#pragma unroll
    for (int off = 1; off < 64; off <<= 1) {
        int u = __shfl_up(s, off, 64);
        if (lane >= off) s += u;
    }
    if (lane == 63) wsum[wid] = s;
    __syncthreads();
    if (wid == 0) {
        int w2 = (lane < 16) ? wsum[lane] : 0;
#pragma unroll
        for (int off = 1; off < 16; off <<= 1) {
            int u = __shfl_up(w2, off, 64);
            if (lane >= off) w2 += u;
        }
        if (lane < 16) woff[lane + 1] = w2;
        if (lane == 0) woff[0] = 0;
    }
    __syncthreads();
    int excl = woff[wid] + (s - v);
    if (t < nb) { cbase[t] = excl; ccur[t] = excl; }
    if (t == 0) { cbase[nb] = woff[16]; rowptr[n] = woff[16]; }
}

// ---------------- coarse scatter: pack (src<<7 | dst&127) into bucket-major ebuf ----------------
__global__ __launch_bounds__(256) void k_scat(const int* __restrict__ src,
                                              const int* __restrict__ dst,
                                              int* __restrict__ ccur,
                                              int* __restrict__ ebuf,
                                              int e, int nb, int nscat) {
    __shared__ int lh[NBK];
    __shared__ int lb[NBK];
    const int t = threadIdx.x;
    const int per = (e + nscat - 1) / nscat;
    const int lo = blockIdx.x * per;
    const int hi = min(e, lo + per);
    for (int i = t; i < NBK; i += 256) lh[i] = 0;
    __syncthreads();
    for (int i = lo + t; i < hi; i += 256) atomicAdd(&lh[dst[i] >> 7], 1);
    __syncthreads();
    for (int i = t; i < nb; i += 256) {
        int c = lh[i];
        lb[i] = c ? atomicAdd(&ccur[i], c) : 0;
    }
    __syncthreads();
    for (int i = t; i < NBK; i += 256) lh[i] = 0;
    __syncthreads();
    for (int i = lo + t; i < hi; i += 256) {
        int d = dst[i];
        int bkt = d >> 7;
        int r = atomicAdd(&lh[bkt], 1);
        ebuf[lb[bkt] + r] = (src[i] << 7) | (d & (CBW - 1));
    }
}

// ---------------- fine counting sort + fused layer-1 alpha ----------------
// While scattering each edge to its final slot, compute w = exp(leaky(as[src]+ad[dst])),
// write ew[pos] = (src<<16)|fp16(w), and accumulate per-dst sums in LDS.
// Then emit invs (1/(sum+wself)) and aself per node.
__global__ __launch_bounds__(256) void k_fine(const int* __restrict__ ebuf,
                                              const int* __restrict__ cbase,
                                              int* __restrict__ rowptr,
                                              int* __restrict__ colidx,
                                              unsigned* __restrict__ ew,
                                              const float* __restrict__ as_,
                                              const float* __restrict__ ad_,
                                              float* __restrict__ invs,
                                              float* __restrict__ aself, int n) {
    const int b = blockIdx.x;
    const int node0 = b * CBW;
    const int nloc = min(CBW, n - node0);
    const int beg = cbase[b], end = cbase[b + 1];
    __shared__ int fh[CBW];
    __shared__ int fo[CBW];
    __shared__ float sums[CBW];
    __shared__ float lad[CBW];
    __shared__ int w0tot;
    const int t = threadIdx.x;
    if (t < CBW) {
        fh[t] = 0;
        sums[t] = 0.f;
        lad[t] = (t < nloc) ? ad_[node0 + t] : 0.f;
    }
    __syncthreads();
    for (int e = beg + t; e < end; e += 256) atomicAdd(&fh[ebuf[e] & (CBW - 1)], 1);
    __syncthreads();
    int v = 0, s = 0;
    if (t < CBW) {
        v = fh[t];
        s = v;
#pragma unroll
        for (int off = 1; off < 64; off <<= 1) {
            int u = __shfl_up(s, off, 64);
            if ((t & 63) >= off) s += u;
        }
        if (t == 63) w0tot = s;
    }
    __syncthreads();
    if (t < CBW) fo[t] = ((t >= 64) ? w0tot : 0) + s - v;
    __syncthreads();
    if (t < nloc) rowptr[node0 + t] = beg + fo[t];
    if (t < CBW) fh[t] = 0;
    __syncthreads();
    for (int e = beg + t; e < end; e += 256) {
        int rec = ebuf[e];
        int d = rec & (CBW - 1);
        int sn = rec >> 7;
        int r = atomicAdd(&fh[d], 1);
        int pos = beg + fo[d] + r;
        colidx[pos] = sn;
        float x = as_[sn] + lad[d];
        x = (x > 0.f) ? x : 0.2f * x;
        float w = __expf(x);
        __half hw = __float2half(w);
        float wq = __half2float(hw);          // sum what aggr will actually use
        ew[pos] = ((unsigned)sn << 16) | (unsigned)__half_as_ushort(hw);
        atomicAdd(&sums[d], wq);
    }
    __syncthreads();
    if (t < nloc) {
        int node = node0 + t;
        float x = as_[node] + lad[t];
        x = (x > 0.f) ? x : 0.2f * x;
        float ws = __expf(x);
        aself[node] = ws;
        invs[node] = 1.f / (sums[t] + ws);
    }
}

// ---------------- layer-2 alpha: wave per node ----------------
__global__ __launch_bounds__(256) void k_alpha(const float* __restrict__ as_,
                                               const float* __restrict__ ad_,
                                               const int* __restrict__ rowptr,
                                               const int* __restrict__ colidx,
                                               unsigned* __restrict__ ew,
                                               float* __restrict__ invs,
                                               float* __restrict__ aself, int n) {
    const int wid = threadIdx.x >> 6;
    const int lane = threadIdx.x & 63;
    const int node = blockIdx.x * 4 + wid;
    if (node >= n) return;
    const float adn = ad_[node];
    const int beg = rowptr[node], end = rowptr[node + 1];
    float sp = 0.f;
    for (int i = beg + lane; i < end; i += 64) {
        int sn = colidx[i];
        float x = as_[sn] + adn;
        x = (x > 0.f) ? x : 0.2f * x;
        float w = __expf(x);
        __half hw = __float2half(w);
        ew[i] = ((unsigned)sn << 16) | (unsigned)__half_as_ushort(hw);
        sp += __half2float(hw);
    }
#pragma unroll
    for (int off = 32; off; off >>= 1) sp += __shfl_xor(sp, off);
    if (lane == 0) {
        float x = as_[node] + adn;
        x = (x > 0.f) ? x : 0.2f * x;
        float ws = __expf(x);
        aself[node] = ws;
        invs[node] = 1.f / (sp + ws);
    }
}

// ---------------- MFMA GEMM (fp16 input) + fused dots ----------------
__global__ __launch_bounds__(256) void k_gemm(const __half* __restrict__ X,
                                              const __half* __restrict__ Wt,
                                              const float* __restrict__ a_s,
                                              const float* __restrict__ a_d,
                                              __half* __restrict__ H,
                                              float* __restrict__ as_,
                                              float* __restrict__ ad_, int n) {
    const int t = threadIdx.x;
    const int wave = t >> 6, lane = t & 63;
    const int g = lane >> 4, c16 = lane & 15;
    const int row0 = blockIdx.x * 64 + wave * 16;
    half8 A[4];
    {
        int row = row0 + c16;
        int rc = (row < n) ? row : (n - 1);
        const __half* xp = &X[(size_t)rc * 128 + g * 8];
#pragma unroll
        for (int kc = 0; kc < 4; kc++) A[kc] = *(const half8*)(xp + kc * 32);
    }
    gemm_core(A, Wt, a_s, a_d, H, as_, ad_, n, row0, g, c16);
}

// ---------------- weighted gather-sum aggregation (split slabs, precomputed weights) ----------------
// Grid = 2*nodeblocks; half = blockIdx&1 binds the feature slab (XCD-parity L2 locality).
// Wave = node; 8 groups x 8 lanes: each group streams its edge subset: one broadcast
// ew load (prefetched 1 ahead) -> 16B H-slab gather -> 8 fma_mix. No exp, no LDS.
__device__ __forceinline__ void fmix8(float* acc, uint4 hv, float w) {
    union { uint4 u; _Float16 h[8]; } c;
    c.u = hv;
#pragma unroll
    for (int j = 0; j < 8; j++) acc[j] += w * (float)c.h[j];
}

__global__ __launch_bounds__(256) void k_aggr(const __half* __restrict__ H,   // [2][n][64]
                                              const unsigned* __restrict__ ew,
                                              const float* __restrict__ aself,
                                              const float* __restrict__ invs,
                                              const int* __restrict__ rowptr,
                                              const float* __restrict__ bias,
                                              float* __restrict__ outf,
                                              __half* __restrict__ outh,
                                              int n, int mode) {   // mode1: relu+fp16 out
    const int half = blockIdx.x & 1;
    const int nblk = blockIdx.x >> 1;
    const int wid = threadIdx.x >> 6;
    const int lane = threadIdx.x & 63;
    const int node = nblk * 4 + wid;
    if (node >= n) return;
    const int g8 = lane >> 3;
    const int l8 = lane & 7;
    const char* Hb = (const char*)H + (size_t)half * ((size_t)n * 128) + l8 * 16;
    float acc[8] = {0.f, 0.f, 0.f, 0.f, 0.f, 0.f, 0.f, 0.f};
    const int beg = rowptr[node], end = rowptr[node + 1];

    if (g8 == 7) {   // self loop
        const uint4 hv = *(const uint4*)(Hb + (unsigned)node * 128u);
        fmix8(acc, hv, aself[node]);
    }

    int i = beg + g8;
    unsigned p = (i < end) ? ew[i] : 0u;
    while (i < end) {
        const unsigned pc = p;
        const int i2 = i + 8;
        if (i2 < end) p = ew[i2];                 // prefetch next pair
        const float w = __half2float(__ushort_as_half((unsigned short)(pc & 0xffffu)));
        const uint4 hv = *(const uint4*)(Hb + (pc >> 16) * 128u);
        fmix8(acc, hv, w);
        i = i2;
    }

#pragma unroll
    for (int off = 8; off <= 32; off <<= 1) {
#pragma unroll
        for (int j = 0; j < 8; j++) acc[j] += __shfl_xor(acc[j], off);
    }
    if (g8 == 0) {
        const float inv = invs[node];
        const int f0 = half * 64 + l8 * 8;
        float o[8];
        const float4 b0 = *(const float4*)&bias[f0];
        const float4 b1 = *(const float4*)&bias[f0 + 4];
        o[0] = acc[0] * inv + b0.x; o[1] = acc[1] * inv + b0.y;
        o[2] = acc[2] * inv + b0.z; o[3] = acc[3] * inv + b0.w;
        o[4] = acc[4] * inv + b1.x; o[5] = acc[5] * inv + b1.y;
        o[6] = acc[6] * inv + b1.z; o[7] = acc[7] * inv + b1.w;
        if (mode == 1) {
#pragma unroll
            for (int j = 0; j < 8; j++) o[j] = fmaxf(o[j], 0.f);
            union { __half2 h2[4]; uint4 u; } pkk;
            pkk.h2[0] = __floats2half2_rn(o[0], o[1]);
            pkk.h2[1] = __floats2half2_rn(o[2], o[3]);
            pkk.h2[2] = __floats2half2_rn(o[4], o[5]);
            pkk.h2[3] = __floats2half2_rn(o[6], o[7]);
            *(uint4*)&outh[(size_t)node * 128 + f0] = pkk.u;
        } else {
            *(float4*)&outf[(size_t)node * 128 + f0] = make_float4(o[0], o[1], o[2], o[3]);
            *(float4*)&outf[(size_t)node * 128 + f0 + 4] = make_float4(o[4], o[5], o[6], o[7]);
        }
    }
}

extern "C" void kernel_launch(void* const* d_in, const int* in_sizes, int n_in,
                              void* d_out, int out_size, void* d_ws, size_t ws_size,
                              hipStream_t stream) {
    const float* x   = (const float*)d_in[0];
    const int*   ei  = (const int*)d_in[1];
    const float* W1  = (const float*)d_in[2];
    const float* a1s = (const float*)d_in[3];
    const float* a1d = (const float*)d_in[4];
    const float* b1  = (const float*)d_in[5];
    const float* W2  = (const float*)d_in[6];
    const float* a2s = (const float*)d_in[7];
    const float* a2d = (const float*)d_in[8];
    const float* b2  = (const float*)d_in[9];
    float* dout = (float*)d_out;

    const int n = in_sizes[0] / FD;          // 50000
    const int E = in_sizes[1] / 2;           // 1600000
    const int* src = ei;
    const int* dst = ei + E;
    const int NB = (n + CBW - 1) / CBW;      // 391 coarse buckets

    // workspace layout
    // buf0 (12.8 MB) time-shared: ebuf (CSR build) -> Y16 (layer1 output)
    char* base = (char*)d_ws;
    __half* buf0  = (__half*)base;                    // n*128 halves
    int*    ebuf  = (int*)base;                       // E ints (6.4 MB), aliases buf0
    __half* H     = (__half*)(base + (size_t)n * FD * sizeof(__half));
    float* as_    = (float*)((char*)H + (size_t)n * FD * sizeof(__half));
    float* ad_    = as_ + n;
    float* invs   = ad_ + n;                 // n
    float* aself  = invs + n;                // n
    int*   rowptr = (int*)(aself + n);       // n+1
    int*   ccnt   = rowptr + (n + 1);        // NB
    int*   cbase  = ccnt + NB;               // NB+1
    int*   ccur   = cbase + NB + 1;          // NB
    int*   colidx = ccur + NB;               // E
    unsigned* ew  = (unsigned*)(colidx + E); // E (6.4 MB)
    size_t wt_off = (((size_t)((char*)(ew + E) - base)) + 15) & ~(size_t)15;
    __half* Wt1h  = (__half*)(base + wt_off);         // 32 KB
    __half* Wt2h  = Wt1h + 128 * 128;                  // 32 KB

    const int gemm_grid = (n + 63) / 64;     // 782
    const int node_grid = (n + 3) / 4;       // 12500
    const int SCAT = 256;

    // ---- D0: W transposes + zero ccnt ----
    k_wz<<<3, 256, 0, stream>>>(W1, W2, Wt1h, Wt2h, ccnt, NB);
    // ---- D1: coarse hist || layer-1 GEMM ----
    k_pg<<<256 + gemm_grid, 256, 0, stream>>>(dst, ccnt, E, NB,
                                              x, Wt1h, a1s, a1d, H, as_, ad_, n);
    // ---- D2: scan ----
    k_cscan<<<1, 1024, 0, stream>>>(ccnt, cbase, ccur, NB, rowptr, n);
    // ---- D3: coarse scatter ----
    k_scat<<<SCAT, 256, 0, stream>>>(src, dst, ccur, ebuf, E, NB, SCAT);
    // ---- D4: fine sort + fused layer-1 alpha ----
    k_fine<<<NB, 256, 0, stream>>>(ebuf, cbase, rowptr, colidx, ew, as_, ad_,
                                   invs, aself, n);
    // ---- D5: layer-1 aggregate (relu, fp16 out into buf0; ebuf dead) ----
    k_aggr<<<node_grid * 2, 256, 0, stream>>>(H, ew, aself, invs, rowptr, b1,
                                              nullptr, buf0, n, 1);
    // ---- D6: layer-2 GEMM ----
    k_gemm<<<gemm_grid, 256, 0, stream>>>(buf0, Wt2h, a2s, a2d, H, as_, ad_, n);
    // ---- D7: layer-2 alpha ----
    k_alpha<<<node_grid, 256, 0, stream>>>(as_, ad_, rowptr, colidx, ew, invs, aself, n);
    // ---- D8: layer-2 aggregate (fp32 out) ----
    k_aggr<<<node_grid * 2, 256, 0, stream>>>(H, ew, aself, invs, rowptr, b2,
                                              dout, nullptr, n, 0);
}

// Round 14
// 210.763 us; speedup vs baseline: 1.1382x; 1.1382x over previous
//
#include <hip/hip_runtime.h>
#include <hip/hip_bf16.h>
#include <hip/hip_fp16.h>

#define FD 128
#define CBW 128           // coarse bucket width: bucket = dst >> 7
#define NBK 512           // max buckets (50000/128 = 391)

typedef _Float16 half8 __attribute__((ext_vector_type(8)));
typedef float f32x4 __attribute__((ext_vector_type(4)));

// ---------------- tiny prep: W1,W2 -> W^T fp16 (blocks 0,1); zero ccnt (block 2) ----------------
__global__ __launch_bounds__(256) void k_wz(const float* __restrict__ W1,
                                            const float* __restrict__ W2,
                                            __half* __restrict__ T1,
                                            __half* __restrict__ T2,
                                            int* __restrict__ ccnt, int nb) {
    const int t = threadIdx.x;
    if (blockIdx.x == 2) {
        for (int i = t; i < nb; i += 256) ccnt[i] = 0;
        return;
    }
    __shared__ float sw[128 * 129];
    const float* W = blockIdx.x ? W2 : W1;
    __half* T = blockIdx.x ? T2 : T1;
#pragma unroll
    for (int i = 0; i < 64; i++) {
        int idx = i * 256 + t;
        sw[(idx >> 7) * 129 + (idx & 127)] = W[idx];
    }
    __syncthreads();
#pragma unroll
    for (int i = 0; i < 32; i++) {
        int o = i * 256 + t;
        int c = o >> 6, kp = o & 63;
        float lo = sw[(kp * 2) * 129 + c];
        float hi = sw[(kp * 2 + 1) * 129 + c];
        *(__half2*)&T[c * 128 + kp * 2] = __floats2half2_rn(lo, hi);
    }
}

__device__ __forceinline__ void gemm_core(const half8 A[4],
                                          const __half* __restrict__ Wt,
                                          const float* __restrict__ a_s,
                                          const float* __restrict__ a_d,
                                          __half* __restrict__ H,
                                          float* __restrict__ as_,
                                          float* __restrict__ ad_,
                                          int n, int row0, int g, int c16) {
    f32x4 acc[8];
#pragma unroll
    for (int ct = 0; ct < 8; ct++) acc[ct] = (f32x4){0.f, 0.f, 0.f, 0.f};
#pragma unroll
    for (int ct = 0; ct < 8; ct++) {
        const __half* wp = &Wt[(ct * 16 + c16) * 128 + g * 8];
#pragma unroll
        for (int kc = 0; kc < 4; kc++) {
            half8 b = *(const half8*)(wp + kc * 32);
            acc[ct] = __builtin_amdgcn_mfma_f32_16x16x32_f16(A[kc], b, acc[ct], 0, 0, 0);
        }
    }
    float asv[8], adv[8];
#pragma unroll
    for (int ct = 0; ct < 8; ct++) {
        asv[ct] = a_s[ct * 16 + c16];
        adv[ct] = a_d[ct * 16 + c16];
    }
#pragma unroll
    for (int r = 0; r < 4; r++) {
        const int row = row0 + g * 4 + r;
        float vs = 0.f, vd = 0.f;
#pragma unroll
        for (int ct = 0; ct < 8; ct++) {
            float v = acc[ct][r];
            vs += v * asv[ct];
            vd += v * adv[ct];
            if (row < n) H[(size_t)row * 128 + ct * 16 + c16] = __float2half(v);
        }
#pragma unroll
        for (int off = 8; off; off >>= 1) {
            vs += __shfl_xor(vs, off, 16);
            vd += __shfl_xor(vd, off, 16);
        }
        if (c16 == 0 && row < n) { as_[row] = vs; ad_[row] = vd; }
    }
}

// ---------------- fat: coarse histogram (blocks 0..255) || layer-1 GEMM (blocks 256+) ----------------
__global__ __launch_bounds__(256) void k_pg(const int* __restrict__ dst,
                                            int* __restrict__ ccnt, int e, int nb,
                                            const float* __restrict__ X,
                                            const __half* __restrict__ Wt,
                                            const float* __restrict__ a_s,
                                            const float* __restrict__ a_d,
                                            __half* __restrict__ H,
                                            float* __restrict__ as_,
                                            float* __restrict__ ad_, int n) {
    __shared__ int lh[NBK];
    const int t = threadIdx.x;
    if (blockIdx.x < 256) {
        for (int i = t; i < NBK; i += 256) lh[i] = 0;
        __syncthreads();
        for (int i = blockIdx.x * 256 + t; i < e; i += 256 * 256)
            atomicAdd(&lh[dst[i] >> 7], 1);
        __syncthreads();
        for (int i = t; i < nb; i += 256) {
            int c = lh[i];
            if (c) atomicAdd(&ccnt[i], c);
        }
    } else {
        const int bid = blockIdx.x - 256;
        const int wave = t >> 6, lane = t & 63;
        const int g = lane >> 4, c16 = lane & 15;
        const int row0 = bid * 64 + wave * 16;
        half8 A[4];
        {
            int row = row0 + c16;
            int rc = (row < n) ? row : (n - 1);
            const float* xp = &X[(size_t)rc * 128 + g * 8];
#pragma unroll
            for (int kc = 0; kc < 4; kc++) {
                float4 x0 = *(const float4*)(xp + kc * 32);
                float4 x1 = *(const float4*)(xp + kc * 32 + 4);
                half8 a;
                a[0] = (_Float16)x0.x; a[1] = (_Float16)x0.y;
                a[2] = (_Float16)x0.z; a[3] = (_Float16)x0.w;
                a[4] = (_Float16)x1.x; a[5] = (_Float16)x1.y;
                a[6] = (_Float16)x1.z; a[7] = (_Float16)x1.w;
                A[kc] = a;
            }
        }
        gemm_core(A, Wt, a_s, a_d, H, as_, ad_, n, row0, g, c16);
    }
}

// ---------------- scan of coarse counts (single block, nb<=1024) ----------------
__global__ void k_cscan(const int* __restrict__ ccnt, int* __restrict__ cbase,
                        int* __restrict__ ccur, int nb, int* __restrict__ rowptr, int n) {
    __shared__ int wsum[16];
    __shared__ int woff[17];
    const int t = threadIdx.x, lane = t & 63, wid = t >> 6;
    int v = (t < nb) ? ccnt[t] : 0;
    int s = v;
#pragma unroll
    for (int off = 1; off < 64; off <<= 1) {
        int u = __shfl_up(s, off, 64);
        if (lane >= off) s += u;
    }
    if (lane == 63) wsum[wid] = s;
    __syncthreads();
    if (wid == 0) {
        int w2 = (lane < 16) ? wsum[lane] : 0;
#pragma unroll
        for (int off = 1; off < 16; off <<= 1) {
            int u = __shfl_up(w2, off, 64);
            if (lane >= off) w2 += u;
        }
        if (lane < 16) woff[lane + 1] = w2;
        if (lane == 0) woff[0] = 0;
    }
    __syncthreads();
    int excl = woff[wid] + (s - v);
    if (t < nb) { cbase[t] = excl; ccur[t] = excl; }
    if (t == 0) { cbase[nb] = woff[16]; rowptr[n] = woff[16]; }
}

// ---------------- coarse scatter: pack (src<<7 | dst&127) into bucket-major ebuf ----------------
__global__ __launch_bounds__(256) void k_scat(const int* __restrict__ src,
                                              const int* __restrict__ dst,
                                              int* __restrict__ ccur,
                                              int* __restrict__ ebuf,
                                              int e, int nb, int nscat) {
    __shared__ int lh[NBK];
    __shared__ int lb[NBK];
    const int t = threadIdx.x;
    const int per = (e + nscat - 1) / nscat;
    const int lo = blockIdx.x * per;
    const int hi = min(e, lo + per);
    for (int i = t; i < NBK; i += 256) lh[i] = 0;
    __syncthreads();
    for (int i = lo + t; i < hi; i += 256) atomicAdd(&lh[dst[i] >> 7], 1);
    __syncthreads();
    for (int i = t; i < nb; i += 256) {
        int c = lh[i];
        lb[i] = c ? atomicAdd(&ccur[i], c) : 0;
    }
    __syncthreads();
    for (int i = t; i < NBK; i += 256) lh[i] = 0;
    __syncthreads();
    for (int i = lo + t; i < hi; i += 256) {
        int d = dst[i];
        int bkt = d >> 7;
        int r = atomicAdd(&lh[bkt], 1);
        ebuf[lb[bkt] + r] = (src[i] << 7) | (d & (CBW - 1));
    }
}

// ---------------- fine counting sort within each coarse bucket (CBW=128) ----------------
__global__ __launch_bounds__(256) void k_fine(const int* __restrict__ ebuf,
                                              const int* __restrict__ cbase,
                                              int* __restrict__ rowptr,
                                              int* __restrict__ colidx, int n) {
    const int b = blockIdx.x;
    const int node0 = b * CBW;
    const int nloc = min(CBW, n - node0);
    const int beg = cbase[b], end = cbase[b + 1];
    __shared__ int fh[CBW];
    __shared__ int fo[CBW];
    __shared__ int w0tot;
    const int t = threadIdx.x;
    if (t < CBW) fh[t] = 0;
    __syncthreads();
    for (int e = beg + t; e < end; e += 256) atomicAdd(&fh[ebuf[e] & (CBW - 1)], 1);
    __syncthreads();
    int v = 0, s = 0;
    if (t < CBW) {
        v = fh[t];
        s = v;
#pragma unroll
        for (int off = 1; off < 64; off <<= 1) {
            int u = __shfl_up(s, off, 64);
            if ((t & 63) >= off) s += u;
        }
        if (t == 63) w0tot = s;
    }
    __syncthreads();
    if (t < CBW) fo[t] = ((t >= 64) ? w0tot : 0) + s - v;
    __syncthreads();
    if (t < nloc) rowptr[node0 + t] = beg + fo[t];
    if (t < CBW) fh[t] = 0;
    __syncthreads();
    for (int e = beg + t; e < end; e += 256) {
        int rec = ebuf[e];
        int d = rec & (CBW - 1);
        int r = atomicAdd(&fh[d], 1);
        colidx[beg + fo[d] + r] = rec >> 7;
    }
}

// ---------------- MFMA GEMM (fp16 input) + fused dots ----------------
__global__ __launch_bounds__(256) void k_gemm(const __half* __restrict__ X,
                                              const __half* __restrict__ Wt,
                                              const float* __restrict__ a_s,
                                              const float* __restrict__ a_d,
                                              __half* __restrict__ H,
                                              float* __restrict__ as_,
                                              float* __restrict__ ad_, int n) {
    const int t = threadIdx.x;
    const int wave = t >> 6, lane = t & 63;
    const int g = lane >> 4, c16 = lane & 15;
    const int row0 = blockIdx.x * 64 + wave * 16;
    half8 A[4];
    {
        int row = row0 + c16;
        int rc = (row < n) ? row : (n - 1);
        const __half* xp = &X[(size_t)rc * 128 + g * 8];
#pragma unroll
        for (int kc = 0; kc < 4; kc++) A[kc] = *(const half8*)(xp + kc * 32);
    }
    gemm_core(A, Wt, a_s, a_d, H, as_, ad_, n, row0, g, c16);
}

// ---------------- fused softmax + aggregation: pipelined phase A, 4-deep phase B ----------------
// Superstep of 64 edges. Phase A (all lanes): one edge each — colidx+as_ gathers for the
// NEXT superstep are issued BEFORE phase B so their latency hides under the H-gather loop;
// exp/LDS-write use already-resident registers. Phase B: each quarter-wave issues 4
// independent H-row loads before consuming (4 outstanding gathers/wave).
// End-normalization exact (softmax shift-invariance; logits bounded).
__device__ __forceinline__ void fmix8(float* acc, uint4 hv, float w) {
    union { uint4 u; _Float16 h[8]; } c;
    c.u = hv;
#pragma unroll
    for (int j = 0; j < 8; j++) acc[j] += w * (float)c.h[j];
}

__global__ __launch_bounds__(256) void k_aggr(const __half* __restrict__ H,
                                              const float* __restrict__ as_,
                                              const float* __restrict__ ad_,
                                              const int* __restrict__ rowptr,
                                              const int* __restrict__ colidx,
                                              const float* __restrict__ bias,
                                              float* __restrict__ outf,
                                              __half* __restrict__ outh,
                                              int n, int mode) {   // mode1: relu+fp16 out
    __shared__ int2 pr[4][64];
    const int wid = threadIdx.x >> 6;
    const int lane = threadIdx.x & 63;
    const int node = blockIdx.x * 4 + wid;
    if (node >= n) return;
    const int q = lane >> 4;
    const int boff = (lane & 15) * 16;
    const char* Hb = (const char*)H + boff;
    const float adn = ad_[node];
    float sp = 0.f;
    float acc[8] = {0.f, 0.f, 0.f, 0.f, 0.f, 0.f, 0.f, 0.f};
    const int beg = rowptr[node], end = rowptr[node + 1];

    // prologue: phase-A loads for superstep 0
    int sl = node;
    float av = 0.f;
    if (beg < end) {
        int idx = beg + lane;
        sl = colidx[(idx < end) ? idx : (end - 1)];
        av = as_[sl];
    }

    {   // self loop (overlaps prologue gathers)
        float e = as_[node] + adn;
        e = (e > 0.f) ? e : 0.2f * e;
        const float w = __expf(e);
        if (lane == 63) sp += w;
        if (q == 3) {
            const uint4 hv = *(const uint4*)(Hb + ((unsigned)node << 8));
            fmix8(acc, hv, w);
        }
    }

    for (int it = beg; it < end; it += 64) {
        // issue phase-A loads for NEXT superstep (latency hides under phase B)
        const int nit = it + 64;
        int nsl = node; float nav = 0.f;
        if (nit < end) {
            int idx2 = nit + lane;
            nsl = colidx[(idx2 < end) ? idx2 : (end - 1)];
            nav = as_[nsl];
        }
        // phase-A compute for CURRENT superstep (registers already resident)
        {
            const bool valid = (it + lane) < end;
            float e = av + adn;
            e = (e > 0.f) ? e : 0.2f * e;
            const float w = valid ? __expf(e) : 0.f;
            sp += w;
            pr[wid][lane] = make_int2((int)((unsigned)sl << 8), __float_as_int(w));
        }
        // phase B: 4-deep gather+accumulate
        int m = end - it; if (m > 64) m = 64;
        const int iters = (m + 3) >> 2;
        int slot = q;
        int g = 0;
        for (; g + 4 <= iters; g += 4) {
            const int2 p0 = pr[wid][slot];
            const int2 p1 = pr[wid][slot + 4];
            const int2 p2 = pr[wid][slot + 8];
            const int2 p3 = pr[wid][slot + 12];
            const uint4 h0 = *(const uint4*)(Hb + (unsigned)p0.x);
            const uint4 h1 = *(const uint4*)(Hb + (unsigned)p1.x);
            const uint4 h2 = *(const uint4*)(Hb + (unsigned)p2.x);
            const uint4 h3 = *(const uint4*)(Hb + (unsigned)p3.x);
            fmix8(acc, h0, __int_as_float(p0.y));
            fmix8(acc, h1, __int_as_float(p1.y));
            fmix8(acc, h2, __int_as_float(p2.y));
            fmix8(acc, h3, __int_as_float(p3.y));
            slot += 16;
        }
        for (; g < iters; ++g) {
            const int2 p = pr[wid][slot];
            const uint4 hv = *(const uint4*)(Hb + (unsigned)p.x);
            fmix8(acc, hv, __int_as_float(p.y));
            slot += 4;
        }
        sl = nsl; av = nav;
    }

#pragma unroll
    for (int off = 1; off < 64; off <<= 1) sp += __shfl_xor(sp, off);
#pragma unroll
    for (int off = 16; off <= 32; off <<= 1) {
#pragma unroll
        for (int j = 0; j < 8; j++) acc[j] += __shfl_xor(acc[j], off);
    }
    if (q == 0) {
        const int f0 = boff >> 1;
        const float inv = 1.f / sp;
        float o[8];
        const float4 b0 = *(const float4*)&bias[f0];
        const float4 b1 = *(const float4*)&bias[f0 + 4];
        o[0] = acc[0] * inv + b0.x; o[1] = acc[1] * inv + b0.y;
        o[2] = acc[2] * inv + b0.z; o[3] = acc[3] * inv + b0.w;
        o[4] = acc[4] * inv + b1.x; o[5] = acc[5] * inv + b1.y;
        o[6] = acc[6] * inv + b1.z; o[7] = acc[7] * inv + b1.w;
        if (mode == 1) {
#pragma unroll
            for (int j = 0; j < 8; j++) o[j] = fmaxf(o[j], 0.f);
            union { __half2 h2[4]; uint4 u; } pkk;
            pkk.h2[0] = __floats2half2_rn(o[0], o[1]);
            pkk.h2[1] = __floats2half2_rn(o[2], o[3]);
            pkk.h2[2] = __floats2half2_rn(o[4], o[5]);
            pkk.h2[3] = __floats2half2_rn(o[6], o[7]);
            *(uint4*)&outh[(size_t)node * 128 + f0] = pkk.u;
        } else {
            *(float4*)&outf[(size_t)node * 128 + f0] = make_float4(o[0], o[1], o[2], o[3]);
            *(float4*)&outf[(size_t)node * 128 + f0 + 4] = make_float4(o[4], o[5], o[6], o[7]);
        }
    }
}

extern "C" void kernel_launch(void* const* d_in, const int* in_sizes, int n_in,
                              void* d_out, int out_size, void* d_ws, size_t ws_size,
                              hipStream_t stream) {
    const float* x   = (const float*)d_in[0];
    const int*   ei  = (const int*)d_in[1];
    const float* W1  = (const float*)d_in[2];
    const float* a1s = (const float*)d_in[3];
    const float* a1d = (const float*)d_in[4];
    const float* b1  = (const float*)d_in[5];
    const float* W2  = (const float*)d_in[6];
    const float* a2s = (const float*)d_in[7];
    const float* a2d = (const float*)d_in[8];
    const float* b2  = (const float*)d_in[9];
    float* dout = (float*)d_out;

    const int n = in_sizes[0] / FD;          // 50000
    const int E = in_sizes[1] / 2;           // 1600000
    const int* src = ei;
    const int* dst = ei + E;
    const int NB = (n + CBW - 1) / CBW;      // 391 coarse buckets

    // workspace layout
    // buf0 (12.8 MB) time-shared: ebuf (CSR build) -> Y16 (layer1 output)
    char* base = (char*)d_ws;
    __half* buf0  = (__half*)base;                    // n*128 halves
    int*    ebuf  = (int*)base;                       // E ints (6.4 MB), aliases buf0
    __half* H     = (__half*)(base + (size_t)n * FD * sizeof(__half));
    float* as_    = (float*)((char*)H + (size_t)n * FD * sizeof(__half));
    float* ad_    = as_ + n;
    int*   rowptr = (int*)(ad_ + n);         // n+1
    int*   ccnt   = rowptr + (n + 1);        // NB
    int*   cbase  = ccnt + NB;               // NB+1
    int*   ccur   = cbase + NB + 1;          // NB
    int*   colidx = ccur + NB;               // E
    size_t wt_off = (((size_t)((char*)(colidx + E) - base)) + 15) & ~(size_t)15;
    __half* Wt1h  = (__half*)(base + wt_off);         // 32 KB
    __half* Wt2h  = Wt1h + 128 * 128;                  // 32 KB

    const int gemm_grid = (n + 63) / 64;     // 782
    const int node_grid = (n + 3) / 4;       // 12500
    const int SCAT = 256;

    // ---- D0: W transposes + zero ccnt (3 tiny blocks) ----
    k_wz<<<3, 256, 0, stream>>>(W1, W2, Wt1h, Wt2h, ccnt, NB);
    // ---- D1: coarse hist || layer-1 GEMM (reads fp32 x, Wt1h) ----
    k_pg<<<256 + gemm_grid, 256, 0, stream>>>(dst, ccnt, E, NB,
                                              x, Wt1h, a1s, a1d, H, as_, ad_, n);
    // ---- D2: scan ----
    k_cscan<<<1, 1024, 0, stream>>>(ccnt, cbase, ccur, NB, rowptr, n);
    // ---- D3: coarse scatter ----
    k_scat<<<SCAT, 256, 0, stream>>>(src, dst, ccur, ebuf, E, NB, SCAT);
    // ---- D4: fine sort -> colidx/rowptr ----
    k_fine<<<NB, 256, 0, stream>>>(ebuf, cbase, rowptr, colidx, n);
    // ---- D5: layer-1 aggregate (relu, fp16 out into buf0; ebuf dead) ----
    k_aggr<<<node_grid, 256, 0, stream>>>(H, as_, ad_, rowptr, colidx, b1,
                                          nullptr, buf0, n, 1);
    // ---- D6: layer-2 GEMM (fp16 input) ----
    k_gemm<<<gemm_grid, 256, 0, stream>>>(buf0, Wt2h, a2s, a2d, H, as_, ad_, n);
    // ---- D7: layer-2 aggregate (fp32 out) ----
    k_aggr<<<node_grid, 256, 0, stream>>>(H, as_, ad_, rowptr, colidx, b2,
                                          dout, nullptr, n, 0);
}

// Round 15
// 205.438 us; speedup vs baseline: 1.1677x; 1.0259x over previous
//
#include <hip/hip_runtime.h>
#include <hip/hip_bf16.h>
#include <hip/hip_fp16.h>

#define FD 128
#define CBW 128           // coarse bucket width: bucket = dst >> 7
#define NBK 512           // max buckets (50000/128 = 391)

typedef _Float16 half8 __attribute__((ext_vector_type(8)));
typedef float f32x4 __attribute__((ext_vector_type(4)));

// ---------------- tiny prep: W1,W2 -> W^T fp16 (blocks 0,1); zero ccnt (block 2) ----------------
__global__ __launch_bounds__(256) void k_wz(const float* __restrict__ W1,
                                            const float* __restrict__ W2,
                                            __half* __restrict__ T1,
                                            __half* __restrict__ T2,
                                            int* __restrict__ ccnt, int nb) {
    const int t = threadIdx.x;
    if (blockIdx.x == 2) {
        for (int i = t; i < nb; i += 256) ccnt[i] = 0;
        return;
    }
    __shared__ float sw[128 * 129];
    const float* W = blockIdx.x ? W2 : W1;
    __half* T = blockIdx.x ? T2 : T1;
#pragma unroll
    for (int i = 0; i < 64; i++) {
        int idx = i * 256 + t;
        sw[(idx >> 7) * 129 + (idx & 127)] = W[idx];
    }
    __syncthreads();
#pragma unroll
    for (int i = 0; i < 32; i++) {
        int o = i * 256 + t;
        int c = o >> 6, kp = o & 63;
        float lo = sw[(kp * 2) * 129 + c];
        float hi = sw[(kp * 2 + 1) * 129 + c];
        *(__half2*)&T[c * 128 + kp * 2] = __floats2half2_rn(lo, hi);
    }
}

__device__ __forceinline__ void gemm_core(const half8 A[4],
                                          const __half* __restrict__ Wt,
                                          const float* __restrict__ a_s,
                                          const float* __restrict__ a_d,
                                          __half* __restrict__ H,
                                          float* __restrict__ as_,
                                          float* __restrict__ ad_,
                                          int n, int row0, int g, int c16) {
    f32x4 acc[8];
#pragma unroll
    for (int ct = 0; ct < 8; ct++) acc[ct] = (f32x4){0.f, 0.f, 0.f, 0.f};
#pragma unroll
    for (int ct = 0; ct < 8; ct++) {
        const __half* wp = &Wt[(ct * 16 + c16) * 128 + g * 8];
#pragma unroll
        for (int kc = 0; kc < 4; kc++) {
            half8 b = *(const half8*)(wp + kc * 32);
            acc[ct] = __builtin_amdgcn_mfma_f32_16x16x32_f16(A[kc], b, acc[ct], 0, 0, 0);
        }
    }
    float asv[8], adv[8];
#pragma unroll
    for (int ct = 0; ct < 8; ct++) {
        asv[ct] = a_s[ct * 16 + c16];
        adv[ct] = a_d[ct * 16 + c16];
    }
#pragma unroll
    for (int r = 0; r < 4; r++) {
        const int row = row0 + g * 4 + r;
        float vs = 0.f, vd = 0.f;
#pragma unroll
        for (int ct = 0; ct < 8; ct++) {
            float v = acc[ct][r];
            vs += v * asv[ct];
            vd += v * adv[ct];
            if (row < n) H[(size_t)row * 128 + ct * 16 + c16] = __float2half(v);
        }
#pragma unroll
        for (int off = 8; off; off >>= 1) {
            vs += __shfl_xor(vs, off, 16);
            vd += __shfl_xor(vd, off, 16);
        }
        if (c16 == 0 && row < n) { as_[row] = vs; ad_[row] = vd; }
    }
}

// ---------------- fat: coarse histogram (blocks 0..255) || layer-1 GEMM (blocks 256+) ----------------
__global__ __launch_bounds__(256) void k_pg(const int* __restrict__ dst,
                                            int* __restrict__ ccnt, int e, int nb,
                                            const float* __restrict__ X,
                                            const __half* __restrict__ Wt,
                                            const float* __restrict__ a_s,
                                            const float* __restrict__ a_d,
                                            __half* __restrict__ H,
                                            float* __restrict__ as_,
                                            float* __restrict__ ad_, int n) {
    __shared__ int lh[NBK];
    const int t = threadIdx.x;
    if (blockIdx.x < 256) {
        for (int i = t; i < NBK; i += 256) lh[i] = 0;
        __syncthreads();
        for (int i = blockIdx.x * 256 + t; i < e; i += 256 * 256)
            atomicAdd(&lh[dst[i] >> 7], 1);
        __syncthreads();
        for (int i = t; i < nb; i += 256) {
            int c = lh[i];
            if (c) atomicAdd(&ccnt[i], c);
        }
    } else {
        const int bid = blockIdx.x - 256;
        const int wave = t >> 6, lane = t & 63;
        const int g = lane >> 4, c16 = lane & 15;
        const int row0 = bid * 64 + wave * 16;
        half8 A[4];
        {
            int row = row0 + c16;
            int rc = (row < n) ? row : (n - 1);
            const float* xp = &X[(size_t)rc * 128 + g * 8];
#pragma unroll
            for (int kc = 0; kc < 4; kc++) {
                float4 x0 = *(const float4*)(xp + kc * 32);
                float4 x1 = *(const float4*)(xp + kc * 32 + 4);
                half8 a;
                a[0] = (_Float16)x0.x; a[1] = (_Float16)x0.y;
                a[2] = (_Float16)x0.z; a[3] = (_Float16)x0.w;
                a[4] = (_Float16)x1.x; a[5] = (_Float16)x1.y;
                a[6] = (_Float16)x1.z; a[7] = (_Float16)x1.w;
                A[kc] = a;
            }
        }
        gemm_core(A, Wt, a_s, a_d, H, as_, ad_, n, row0, g, c16);
    }
}

// ---------------- scan of coarse counts (single block, nb<=1024) ----------------
__global__ void k_cscan(const int* __restrict__ ccnt, int* __restrict__ cbase,
                        int* __restrict__ ccur, int nb, int* __restrict__ rowptr, int n) {
    __shared__ int wsum[16];
    __shared__ int woff[17];
    const int t = threadIdx.x, lane = t & 63, wid = t >> 6;
    int v = (t < nb) ? ccnt[t] : 0;
    int s = v;
#pragma unroll
    for (int off = 1; off < 64; off <<= 1) {
        int u = __shfl_up(s, off, 64);
        if (lane >= off) s += u;
    }
    if (lane == 63) wsum[wid] = s;
    __syncthreads();
    if (wid == 0) {
        int w2 = (lane < 16) ? wsum[lane] : 0;
#pragma unroll
        for (int off = 1; off < 16; off <<= 1) {
            int u = __shfl_up(w2, off, 64);
            if (lane >= off) w2 += u;
        }
        if (lane < 16) woff[lane + 1] = w2;
        if (lane == 0) woff[0] = 0;
    }
    __syncthreads();
    int excl = woff[wid] + (s - v);
    if (t < nb) { cbase[t] = excl; ccur[t] = excl; }
    if (t == 0) { cbase[nb] = woff[16]; rowptr[n] = woff[16]; }
}

// ---------------- coarse scatter: pack (src<<7 | dst&127) into bucket-major ebuf ----------------
__global__ __launch_bounds__(256) void k_scat(const int* __restrict__ src,
                                              const int* __restrict__ dst,
                                              int* __restrict__ ccur,
                                              int* __restrict__ ebuf,
                                              int e, int nb, int nscat) {
    __shared__ int lh[NBK];
    __shared__ int lb[NBK];
    const int t = threadIdx.x;
    const int per = (e + nscat - 1) / nscat;
    const int lo = blockIdx.x * per;
    const int hi = min(e, lo + per);
    for (int i = t; i < NBK; i += 256) lh[i] = 0;
    __syncthreads();
    for (int i = lo + t; i < hi; i += 256) atomicAdd(&lh[dst[i] >> 7], 1);
    __syncthreads();
    for (int i = t; i < nb; i += 256) {
        int c = lh[i];
        lb[i] = c ? atomicAdd(&ccur[i], c) : 0;
    }
    __syncthreads();
    for (int i = t; i < NBK; i += 256) lh[i] = 0;
    __syncthreads();
    for (int i = lo + t; i < hi; i += 256) {
        int d = dst[i];
        int bkt = d >> 7;
        int r = atomicAdd(&lh[bkt], 1);
        ebuf[lb[bkt] + r] = (src[i] << 7) | (d & (CBW - 1));
    }
}

// ---------------- fine counting sort within each coarse bucket (CBW=128) ----------------
__global__ __launch_bounds__(256) void k_fine(const int* __restrict__ ebuf,
                                              const int* __restrict__ cbase,
                                              int* __restrict__ rowptr,
                                              int* __restrict__ colidx, int n) {
    const int b = blockIdx.x;
    const int node0 = b * CBW;
    const int nloc = min(CBW, n - node0);
    const int beg = cbase[b], end = cbase[b + 1];
    __shared__ int fh[CBW];
    __shared__ int fo[CBW];
    __shared__ int w0tot;
    const int t = threadIdx.x;
    if (t < CBW) fh[t] = 0;
    __syncthreads();
    for (int e = beg + t; e < end; e += 256) atomicAdd(&fh[ebuf[e] & (CBW - 1)], 1);
    __syncthreads();
    int v = 0, s = 0;
    if (t < CBW) {
        v = fh[t];
        s = v;
#pragma unroll
        for (int off = 1; off < 64; off <<= 1) {
            int u = __shfl_up(s, off, 64);
            if ((t & 63) >= off) s += u;
        }
        if (t == 63) w0tot = s;
    }
    __syncthreads();
    if (t < CBW) fo[t] = ((t >= 64) ? w0tot : 0) + s - v;
    __syncthreads();
    if (t < nloc) rowptr[node0 + t] = beg + fo[t];
    if (t < CBW) fh[t] = 0;
    __syncthreads();
    for (int e = beg + t; e < end; e += 256) {
        int rec = ebuf[e];
        int d = rec & (CBW - 1);
        int r = atomicAdd(&fh[d], 1);
        colidx[beg + fo[d] + r] = rec >> 7;
    }
}

// ---------------- MFMA GEMM (fp16 input) + fused dots ----------------
__global__ __launch_bounds__(256) void k_gemm(const __half* __restrict__ X,
                                              const __half* __restrict__ Wt,
                                              const float* __restrict__ a_s,
                                              const float* __restrict__ a_d,
                                              __half* __restrict__ H,
                                              float* __restrict__ as_,
                                              float* __restrict__ ad_, int n) {
    const int t = threadIdx.x;
    const int wave = t >> 6, lane = t & 63;
    const int g = lane >> 4, c16 = lane & 15;
    const int row0 = blockIdx.x * 64 + wave * 16;
    half8 A[4];
    {
        int row = row0 + c16;
        int rc = (row < n) ? row : (n - 1);
        const __half* xp = &X[(size_t)rc * 128 + g * 8];
#pragma unroll
        for (int kc = 0; kc < 4; kc++) A[kc] = *(const half8*)(xp + kc * 32);
    }
    gemm_core(A, Wt, a_s, a_d, H, as_, ad_, n, row0, g, c16);
}

// ---------------- fused softmax + aggregation (LDS-routed (off,w) pairs) ----------------
// r11-proven structure: superstep of 64 edges; phase A one-edge-per-lane (one exp/edge,
// LDS pair write), phase B quarter-wave broadcast ds_read + 16B H gather + fma_mix.
// Empirically at the L3 random-line gather ceiling (~3.4 TB/s): 4 structurally
// different variants (r9/r12/r13/r14) all land 53.6-58 us.
__device__ __forceinline__ void fmix8(float* acc, uint4 hv, float w) {
    union { uint4 u; _Float16 h[8]; } c;
    c.u = hv;
#pragma unroll
    for (int j = 0; j < 8; j++) acc[j] += w * (float)c.h[j];
}

__global__ __launch_bounds__(256) void k_aggr(const __half* __restrict__ H,
                                              const float* __restrict__ as_,
                                              const float* __restrict__ ad_,
                                              const int* __restrict__ rowptr,
                                              const int* __restrict__ colidx,
                                              const float* __restrict__ bias,
                                              float* __restrict__ outf,
                                              __half* __restrict__ outh,
                                              int n, int mode) {   // mode1: relu+fp16 out
    __shared__ int2 pr[4][64];
    const int wid = threadIdx.x >> 6;
    const int lane = threadIdx.x & 63;
    const int node = blockIdx.x * 4 + wid;
    if (node >= n) return;
    const int q = lane >> 4;
    const int boff = (lane & 15) * 16;
    const char* Hb = (const char*)H + boff;
    const float adn = ad_[node];
    float sp = 0.f;
    float acc[8] = {0.f, 0.f, 0.f, 0.f, 0.f, 0.f, 0.f, 0.f};
    const int beg = rowptr[node], end = rowptr[node + 1];

    {   // self loop
        float e = as_[node] + adn;
        e = (e > 0.f) ? e : 0.2f * e;
        const float w = __expf(e);
        if (lane == 63) sp += w;
        if (q == 3) {
            const uint4 hv = *(const uint4*)(Hb + ((unsigned)node << 8));
            fmix8(acc, hv, w);
        }
    }

    for (int it = beg; it < end; it += 64) {
        const int idx = it + lane;
        const bool valid = idx < end;
        const int sl = colidx[valid ? idx : (end - 1)];
        float e = as_[sl] + adn;
        e = (e > 0.f) ? e : 0.2f * e;
        const float w = valid ? __expf(e) : 0.f;
        sp += w;
        pr[wid][lane] = make_int2((int)((unsigned)sl << 8), __float_as_int(w));
        int m = end - it; if (m > 64) m = 64;
        const int iters = (m + 3) >> 2;
        int slot = q;
#pragma unroll 4
        for (int g = 0; g < iters; ++g) {
            const int2 p = pr[wid][slot];
            const float wg = __int_as_float(p.y);
            const uint4 hv = *(const uint4*)(Hb + (unsigned)p.x);
            fmix8(acc, hv, wg);
            slot += 4;
        }
    }

#pragma unroll
    for (int off = 1; off < 64; off <<= 1) sp += __shfl_xor(sp, off);
#pragma unroll
    for (int off = 16; off <= 32; off <<= 1) {
#pragma unroll
        for (int j = 0; j < 8; j++) acc[j] += __shfl_xor(acc[j], off);
    }
    if (q == 0) {
        const int f0 = boff >> 1;
        const float inv = 1.f / sp;
        float o[8];
        const float4 b0 = *(const float4*)&bias[f0];
        const float4 b1 = *(const float4*)&bias[f0 + 4];
        o[0] = acc[0] * inv + b0.x; o[1] = acc[1] * inv + b0.y;
        o[2] = acc[2] * inv + b0.z; o[3] = acc[3] * inv + b0.w;
        o[4] = acc[4] * inv + b1.x; o[5] = acc[5] * inv + b1.y;
        o[6] = acc[6] * inv + b1.z; o[7] = acc[7] * inv + b1.w;
        if (mode == 1) {
#pragma unroll
            for (int j = 0; j < 8; j++) o[j] = fmaxf(o[j], 0.f);
            union { __half2 h2[4]; uint4 u; } pkk;
            pkk.h2[0] = __floats2half2_rn(o[0], o[1]);
            pkk.h2[1] = __floats2half2_rn(o[2], o[3]);
            pkk.h2[2] = __floats2half2_rn(o[4], o[5]);
            pkk.h2[3] = __floats2half2_rn(o[6], o[7]);
            *(uint4*)&outh[(size_t)node * 128 + f0] = pkk.u;
        } else {
            *(float4*)&outf[(size_t)node * 128 + f0] = make_float4(o[0], o[1], o[2], o[3]);
            *(float4*)&outf[(size_t)node * 128 + f0 + 4] = make_float4(o[4], o[5], o[6], o[7]);
        }
    }
}

extern "C" void kernel_launch(void* const* d_in, const int* in_sizes, int n_in,
                              void* d_out, int out_size, void* d_ws, size_t ws_size,
                              hipStream_t stream) {
    const float* x   = (const float*)d_in[0];
    const int*   ei  = (const int*)d_in[1];
    const float* W1  = (const float*)d_in[2];
    const float* a1s = (const float*)d_in[3];
    const float* a1d = (const float*)d_in[4];
    const float* b1  = (const float*)d_in[5];
    const float* W2  = (const float*)d_in[6];
    const float* a2s = (const float*)d_in[7];
    const float* a2d = (const float*)d_in[8];
    const float* b2  = (const float*)d_in[9];
    float* dout = (float*)d_out;

    const int n = in_sizes[0] / FD;          // 50000
    const int E = in_sizes[1] / 2;           // 1600000
    const int* src = ei;
    const int* dst = ei + E;
    const int NB = (n + CBW - 1) / CBW;      // 391 coarse buckets

    // workspace layout
    // buf0 (12.8 MB) time-shared: ebuf (CSR build) -> Y16 (layer1 output)
    char* base = (char*)d_ws;
    __half* buf0  = (__half*)base;                    // n*128 halves
    int*    ebuf  = (int*)base;                       // E ints (6.4 MB), aliases buf0
    __half* H     = (__half*)(base + (size_t)n * FD * sizeof(__half));
    float* as_    = (float*)((char*)H + (size_t)n * FD * sizeof(__half));
    float* ad_    = as_ + n;
    int*   rowptr = (int*)(ad_ + n);         // n+1
    int*   ccnt   = rowptr + (n + 1);        // NB
    int*   cbase  = ccnt + NB;               // NB+1
    int*   ccur   = cbase + NB + 1;          // NB
    int*   colidx = ccur + NB;               // E
    size_t wt_off = (((size_t)((char*)(colidx + E) - base)) + 15) & ~(size_t)15;
    __half* Wt1h  = (__half*)(base + wt_off);         // 32 KB
    __half* Wt2h  = Wt1h + 128 * 128;                  // 32 KB

    const int gemm_grid = (n + 63) / 64;     // 782
    const int node_grid = (n + 3) / 4;       // 12500
    const int SCAT = 512;

    // ---- D0: W transposes + zero ccnt (3 tiny blocks) ----
    k_wz<<<3, 256, 0, stream>>>(W1, W2, Wt1h, Wt2h, ccnt, NB);
    // ---- D1: coarse hist || layer-1 GEMM (reads fp32 x, Wt1h) ----
    k_pg<<<256 + gemm_grid, 256, 0, stream>>>(dst, ccnt, E, NB,
                                              x, Wt1h, a1s, a1d, H, as_, ad_, n);
    // ---- D2: scan ----
    k_cscan<<<1, 1024, 0, stream>>>(ccnt, cbase, ccur, NB, rowptr, n);
    // ---- D3: coarse scatter ----
    k_scat<<<SCAT, 256, 0, stream>>>(src, dst, ccur, ebuf, E, NB, SCAT);
    // ---- D4: fine sort -> colidx/rowptr ----
    k_fine<<<NB, 256, 0, stream>>>(ebuf, cbase, rowptr, colidx, n);
    // ---- D5: layer-1 aggregate (relu, fp16 out into buf0; ebuf dead) ----
    k_aggr<<<node_grid, 256, 0, stream>>>(H, as_, ad_, rowptr, colidx, b1,
                                          nullptr, buf0, n, 1);
    // ---- D6: layer-2 GEMM (fp16 input) ----
    k_gemm<<<gemm_grid, 256, 0, stream>>>(buf0, Wt2h, a2s, a2d, H, as_, ad_, n);
    // ---- D7: layer-2 aggregate (fp32 out) ----
    k_aggr<<<node_grid, 256, 0, stream>>>(H, as_, ad_, rowptr, colidx, b2,
                                          dout, nullptr, n, 0);
}